// Round 12
// baseline (135.246 us; speedup 1.0000x reference)
//
#include <hip/hip_runtime.h>

#define BB 32
#define LL 4096
#define DD 512
#define NUM 32
#define KK 5
#define RPB 4   // row-PAIRS per combine block (8 rows, never crosses a batch)

typedef float f32x4 __attribute__((ext_vector_type(4)));

// lags = trunc(linspace(1, 168, 32)) -- precomputed, verified margins >= 0.03
__device__ __constant__ int d_LAGS[NUM] = {
    1, 6, 11, 17, 22, 27, 33, 38, 44, 49, 54, 60, 65, 71, 76, 81,
    87, 92, 97, 103, 108, 114, 119, 124, 130, 135, 141, 146, 151, 157, 162, 168};

// ---------------- Kernel 1: row means over D ----------------
// R12 change: one wave handles TWO rows (4 independent 16B loads/lane, two
// independent shfl-reduce trees) -> 2x memory-level parallelism per wave vs
// the 2-load version. 8 rows per 256-thread block, 16384 blocks.
// Per-row reduction pairing identical to R5/R11 -> bit-identical xm.
// Regular (caching) loads on purpose: populates L3 with x for combine.
__global__ __launch_bounds__(256) void k_mean(const float* __restrict__ x,
                                              float* __restrict__ xm) {
    int wv   = blockIdx.x * 4 + (threadIdx.x >> 6);   // wave id [0, B*L/2)
    int lane = threadIdx.x & 63;
    int row0 = wv * 2;
    const float* p0 = x + (size_t)row0 * DD;
    const float* p1 = p0 + DD;
    // 4 independent loads in flight
    f32x4 a0 = *reinterpret_cast<const f32x4*>(p0 + 4 * lane);
    f32x4 b0 = *reinterpret_cast<const f32x4*>(p0 + 4 * lane + 256);
    f32x4 a1 = *reinterpret_cast<const f32x4*>(p1 + 4 * lane);
    f32x4 b1 = *reinterpret_cast<const f32x4*>(p1 + 4 * lane + 256);
    float s0 = (a0.x + a0.y) + (a0.z + a0.w) + (b0.x + b0.y) + (b0.z + b0.w);
    float s1 = (a1.x + a1.y) + (a1.z + a1.w) + (b1.x + b1.y) + (b1.z + b1.w);
#pragma unroll
    for (int off = 32; off > 0; off >>= 1) {
        s0 += __shfl_down(s0, off, 64);   // two independent chains interleave
        s1 += __shfl_down(s1, off, 64);
    }
    if (lane == 0) {
        xm[row0]     = s0 * (1.0f / DD);
        xm[row0 + 1] = s1 * (1.0f / DD);
    }
}

// ---------------- Kernel 2: autocorrelation scores ----------------
// One block per (batch, lag-candidate); 1024 blocks -> enough TLP to hide
// global-load latency (R4 lesson: low-block-count versions are latency-bound).
__global__ __launch_bounds__(256) void k_scores(const float* __restrict__ xm,
                                                float* __restrict__ scores) {
    int b   = blockIdx.x >> 5;   // / NUM
    int k   = blockIdx.x & 31;   // % NUM
    int lag = d_LAGS[k];
    const float* row = xm + b * LL;
    int n = LL - lag;
    float s = 0.0f;
    for (int t = threadIdx.x; t < n; t += 256) s += row[t] * row[t + lag];
#pragma unroll
    for (int off = 32; off > 0; off >>= 1) s += __shfl_down(s, off, 64);
    __shared__ float red[4];
    int wid = threadIdx.x >> 6, lane = threadIdx.x & 63;
    if (lane == 0) red[wid] = s;
    __syncthreads();
    if (threadIdx.x == 0) {
        float tot = (red[0] + red[1]) + (red[2] + red[3]);
        scores[blockIdx.x] = tot / (float)n;
    }
}

// ---------------- Kernel 3: per-batch top-5 + weights ----------------
// One thread per batch (B=32), ONE block total. 4 us launch is cheaper than
// any inlining attempt (R8: scratch 312us; R9: VALU-issue 306us; R10:
// per-block prologue tax +38us). Tie-break smallest index (lax.top_k).
__global__ __launch_bounds__(64) void k_topk(const float* __restrict__ scores,
                                             float* __restrict__ w,
                                             int* __restrict__ sel) {
    int b = threadIdx.x;
    if (b >= BB) return;
    float sc[NUM];
#pragma unroll
    for (int i = 0; i < NUM; i++) sc[i] = scores[b * NUM + i];
    float vals[KK];
    int idx[KK];
#pragma unroll
    for (int j = 0; j < KK; j++) {
        float best = -INFINITY;
        int bi = 0;
#pragma unroll
        for (int i = 0; i < NUM; i++) {
            if (sc[i] > best) { best = sc[i]; bi = i; }
        }
        vals[j] = best;
        idx[j]  = bi;
        sc[bi]  = -INFINITY;
    }
    float sum = 0.0f;
#pragma unroll
    for (int j = 0; j < KK; j++) sum += vals[j];
    float den = sum + 1e-6f;
#pragma unroll
    for (int j = 0; j < KK; j++) {
        w[b * KK + j]   = vals[j] / den;
        sel[b * KK + j] = d_LAGS[idx[j]];
    }
}

// ---------------- Kernel 4: weighted sum of 5 rolls ----------------
// Each 256-thread block handles RPB=4 consecutive row-pairs (8 rows) -> 8192
// blocks (R11: neutral vs 65536, kept). XCD-contiguous swizzle: each XCD owns
// 1024 consecutive quads = 2 whole batches -> lagged source rows (span <=168)
// stay in its L2. Output stores NON-TEMPORAL: bypass caches so x stays
// L3-resident (R6/R7: FETCH ~273 MB/replay = x read from HBM once).
__global__ __launch_bounds__(256) void k_combine(const float* __restrict__ x,
                                                 const float* __restrict__ w,
                                                 const int* __restrict__ sel,
                                                 float* __restrict__ out) {
    unsigned bid = blockIdx.x;                            // [0, 8192)
    const unsigned GRP_PER_XCD = (BB * LL / 2 / RPB) / 8; // 1024
    unsigned gid   = (bid & 7u) * GRP_PER_XCD + (bid >> 3);
    unsigned pair0 = gid * RPB;                           // first row-pair
    unsigned r0    = pair0 * 2;                           // first row (mult of 8)
    int b = (int)(r0 >> 12);     // batch (8-row group never crosses boundary)

    __shared__ float ww[KK];
    __shared__ int   llag[KK];
    if (threadIdx.x < KK) {
        ww[threadIdx.x]   = w[b * KK + threadIdx.x];
        llag[threadIdx.x] = sel[b * KK + threadIdx.x];
    }
    __syncthreads();

    float wreg[KK];
    int   lreg[KK];
#pragma unroll
    for (int j = 0; j < KK; j++) { wreg[j] = ww[j]; lreg[j] = llag[j]; }

    const float* xb = x + (size_t)b * (LL * DD);
    float* ob = out + (size_t)b * (LL * DD);
    const int half = threadIdx.x >> 7;   // 0..1
    const int d4   = threadIdx.x & 127;
    const int t0   = (int)(r0 & 4095u);  // local row of first pair

#pragma unroll
    for (int i = 0; i < RPB; i++) {
        int t = t0 + i * 2 + half;       // local row in [0, 4096)
        f32x4 acc = {0.f, 0.f, 0.f, 0.f};
#pragma unroll
        for (int j = 0; j < KK; j++) {
            int src = (t - lreg[j]) & (LL - 1);   // roll(+lag)
            f32x4 v = *reinterpret_cast<const f32x4*>(xb + (size_t)src * DD + 4 * d4);
            float wj = wreg[j];
            acc.x += wj * v.x;
            acc.y += wj * v.y;
            acc.z += wj * v.z;
            acc.w += wj * v.w;
        }
        __builtin_nontemporal_store(acc,
            reinterpret_cast<f32x4*>(ob + (size_t)t * DD + 4 * d4));
    }
}

extern "C" void kernel_launch(void* const* d_in, const int* in_sizes, int n_in,
                              void* d_out, int out_size, void* d_ws, size_t ws_size,
                              hipStream_t stream) {
    const float* x = (const float*)d_in[0];
    float* out = (float*)d_out;

    // workspace layout (all fp32/int32, < 1 MB total)
    char* ws = (char*)d_ws;
    float* xm     = (float*)(ws);                         // B*L floats   = 512 KB
    float* scores = (float*)(ws + (size_t)BB * LL * 4);   // B*NUM floats = 4 KB
    float* wts    = (float*)(ws + (size_t)BB * LL * 4 + BB * NUM * 4);        // B*K
    int*   sel    = (int*)  (ws + (size_t)BB * LL * 4 + BB * NUM * 4 + BB * KK * 4);

    k_mean<<<(BB * LL) / 8, 256, 0, stream>>>(x, xm);
    k_scores<<<BB * NUM, 256, 0, stream>>>(xm, scores);
    k_topk<<<1, 64, 0, stream>>>(scores, wts, sel);
    k_combine<<<(BB * LL) / (2 * RPB), 256, 0, stream>>>(x, wts, sel, out);
}